// Round 2
// baseline (375.481 us; speedup 1.0000x reference)
//
#include <hip/hip_runtime.h>

#define B_ 8
#define K_ 100000
#define NODES (B_ * K_)
#define C_ 16
#define O_ 16
#define H_ 512
#define W_ 512
#define TSX 32
#define TSY 16
#define NTX (W_ / TSX)          // 16 tile cols
#define NTY (H_ / TSY)          // 32 tile rows
#define NBKT (B_ * NTX * NTY)   // 4096 buckets
#define CAP 512                 // slots/bucket, PRE path (lambda≈233)
#define EX (TSX + 2)            // 34
#define EY (TSY + 2)            // 18
#define PLANE (EX * EY)         // 612

// ---- PRE fallback path config (round-1 layout) ----
#define FB 1000
#define FPB (FB / B_)           // 125
#define FCHUNK (K_ / FPB)       // 800
#define IDS_OFF 16384
#define P_OFF (IDS_OFF + NBKT * CAP * 4)                 // 8,404,992
#define WS_NEED_PRE ((size_t)P_OFF + (size_t)NODES * O_ * 4) // 59,604,992

// ---- SCAT path config: payload written directly into bucket slots ----
// ws layout: [0..16KB) cursor | [16KB..) lxy u16[NBKT*scap] | slots f32[NBKT*scap*16]
#define SFB 2000
#define SFPB (SFB / B_)         // 250
#define SFCHUNK (K_ / SFPB)     // 400
#define LXY_OFF 16384
static inline size_t ws_need_scat(int scap) {
    return (size_t)LXY_OFF + (size_t)NBKT * scap * 2 + (size_t)NBKT * scap * 64;
}

__device__ __forceinline__ float bf_lo(unsigned int u) {
    union { unsigned int i; float f; } v; v.i = u << 16; return v.f;
}
__device__ __forceinline__ float bf_hi(unsigned int u) {
    union { unsigned int i; float f; } v; v.i = u & 0xffff0000u; return v.f;
}
__device__ __forceinline__ unsigned short f2bf(float f) {
    union { float f; unsigned int u; } v; v.f = f;
    unsigned int u = v.u;
    u += 0x7fffu + ((u >> 16) & 1u);   // round-to-nearest-even
    return (unsigned short)(u >> 16);
}

// Barrier-free dtype probe: bf16 xy pairs always decode (low half) into
// [0,512]; fp32 low halves are random mantissa -> P(all 256 pass)≈1e-146.
// Per-wave __ballot: identical verdict in every wave, no LDS, no barrier.
__device__ __forceinline__ int probe_fp32_ballot(const unsigned int* xy) {
    const int lane = threadIdx.x & 63;
    int bad = 0;
    #pragma unroll
    for (int k = 0; k < 4; ++k) {
        float lo = bf_lo(xy[lane + (k << 6)]);
        bad |= !(lo >= 0.0f && lo <= 512.0f);
    }
    return __ballot(bad) != 0ull;
}

__device__ __forceinline__ void decode_xy(const void* xy, int fp32, int n,
                                          int& xs, int& ys)
{
    float x, y;
    if (fp32) { float2 p = ((const float2*)xy)[n]; x = p.x; y = p.y; }
    else { unsigned int u = ((const unsigned int*)xy)[n]; x = bf_lo(u); y = bf_hi(u); }
    xs = min(max((int)rintf(x), 0), W_ - 1);   // rintf == round-half-even == jnp.round
    ys = min(max((int)rintf(y), 0), H_ - 1);
}

__device__ __forceinline__ void load_feat16(const void* feat, size_t n, int fp32,
                                            float* f)
{
    if (fp32) {
        const float4* ff = (const float4*)feat + n * 4;
        float4 a = ff[0], b2 = ff[1], c = ff[2], d = ff[3];
        f[0]=a.x; f[1]=a.y; f[2]=a.z; f[3]=a.w;
        f[4]=b2.x; f[5]=b2.y; f[6]=b2.z; f[7]=b2.w;
        f[8]=c.x; f[9]=c.y; f[10]=c.z; f[11]=c.w;
        f[12]=d.x; f[13]=d.y; f[14]=d.z; f[15]=d.w;
    } else {
        const uint4* ff = (const uint4*)feat + n * 2;
        uint4 A = ff[0], Bv = ff[1];
        f[0]=bf_lo(A.x);  f[1]=bf_hi(A.x);  f[2]=bf_lo(A.y);  f[3]=bf_hi(A.y);
        f[4]=bf_lo(A.z);  f[5]=bf_hi(A.z);  f[6]=bf_lo(A.w);  f[7]=bf_hi(A.w);
        f[8]=bf_lo(Bv.x); f[9]=bf_hi(Bv.x); f[10]=bf_lo(Bv.y); f[11]=bf_hi(Bv.y);
        f[12]=bf_lo(Bv.z); f[13]=bf_hi(Bv.z); f[14]=bf_lo(Bv.w); f[15]=bf_hi(Bv.w);
    }
}

__device__ __forceinline__ void load_weights_lds(float* wl, int fp32,
                                                 const void* w_obj,
                                                 const void* w_prior,
                                                 int tid, int nthreads)
{
    for (int i = tid; i < 2 * O_ * C_; i += nthreads) {
        if (fp32) {
            wl[i] = (i < O_ * C_) ? ((const float*)w_obj)[i]
                                  : ((const float*)w_prior)[i - O_ * C_];
        } else {
            unsigned short raw = (i < O_ * C_)
                ? ((const unsigned short*)w_obj)[i]
                : ((const unsigned short*)w_prior)[i - O_ * C_];
            union { unsigned int u; float f; } v; v.u = ((unsigned int)raw) << 16;
            wl[i] = v.f;
        }
    }
}

// ===========================================================================
// SCAT pass 1: single-pass bin + project + scatter PAYLOAD into bucket slots.
// feat read coalesced; slot writes are scattered 64B fire-and-forget (L2/L3
// absorbs); no LDS histogram, no reserve pass, no ids indirection.
// ===========================================================================
__global__ __launch_bounds__(256) void fill_scat(
    const void* __restrict__ feat, const void* __restrict__ xy,
    const int* __restrict__ types,
    const void* __restrict__ w_obj, const void* __restrict__ w_prior,
    int* __restrict__ cursor, float* __restrict__ slots,
    unsigned short* __restrict__ lxy, int scap)
{
    __shared__ float wl[2 * O_ * C_];

    const int tid = threadIdx.x;
    const int fp32 = probe_fp32_ballot((const unsigned int*)xy);
    load_weights_lds(wl, fp32, w_obj, w_prior, tid, 256);
    __syncthreads();

    const int bb = blockIdx.x / SFPB;
    const int local0 = (blockIdx.x % SFPB) * SFCHUNK;
    const int s = bb * K_ + local0;

    for (int ii = tid; ii < SFCHUNK; ii += 256) {
        const int n = s + ii;
        int xs, ys; decode_xy(xy, fp32, n, xs, ys);
        const int t = (types[n] != 0);

        float f[16];
        load_feat16(feat, (size_t)n, fp32, f);
        const float* wrow = &wl[t * O_ * C_];
        float pv[16];
        #pragma unroll
        for (int o = 0; o < O_; ++o) {
            float acc = 0.f;
            #pragma unroll
            for (int c = 0; c < C_; ++c) acc = fmaf(wrow[o * C_ + c], f[c], acc);
            pv[o] = acc;
        }

        const int xlo = max((xs - 1) >> 5, 0), xhi = min((xs + 1) >> 5, NTX - 1);
        const int ylo = max((ys - 1) >> 4, 0), yhi = min((ys + 1) >> 4, NTY - 1);
        for (int tyy = ylo; tyy <= yhi; ++tyy)
            for (int txx = xlo; txx <= xhi; ++txx) {
                const int bkg = (bb * NTY + tyy) * NTX + txx;
                const int slot = atomicAdd(&cursor[bkg], 1);
                if (slot < scap) {
                    const size_t base = (size_t)bkg * scap + slot;
                    float4* sp = (float4*)(slots + base * 16);
                    sp[0] = make_float4(pv[0],  pv[1],  pv[2],  pv[3]);
                    sp[1] = make_float4(pv[4],  pv[5],  pv[6],  pv[7]);
                    sp[2] = make_float4(pv[8],  pv[9],  pv[10], pv[11]);
                    sp[3] = make_float4(pv[12], pv[13], pv[14], pv[15]);
                    const int lx = xs - (txx << 5) + 1;   // [0,33]
                    const int ly = ys - (tyy << 4) + 1;   // [0,17]
                    lxy[base] = (unsigned short)(lx | (ly << 8));
                }
            }
    }
}

// ===========================================================================
// SCAT pass 2: per 32x16 tile. ZERO dependent loads: slot/lxy address is a
// pure function of tid -> fully coalesced (4KB/wave) L3-resident reads.
// Then LDS scatter-accumulate, 3x3 conv in LDS, nontemporal store.
// ===========================================================================
__global__ __launch_bounds__(512) void tile_scat(
    const float* __restrict__ slots, const unsigned short* __restrict__ lxy,
    const void* __restrict__ xy,
    const int* __restrict__ cursor, void* __restrict__ out, int scap)
{
    __shared__ float accs[O_ * PLANE];               // 39,168 B -> 4 blocks/CU

    const int tid = threadIdx.x;
    const int tx = blockIdx.x, ty = blockIdx.y, b = blockIdx.z;
    const int bucket = (b * NTY + ty) * NTX + tx;
    int cnt = cursor[bucket];
    if (cnt > scap) cnt = scap;
    const int fp32 = probe_fp32_ballot((const unsigned int*)xy);

    // early issue: coalesced payload loads, zero-fill covers their latency
    float f[16];
    int lx = 0, ly = 0;
    const bool active = (tid < cnt);
    if (active) {
        const size_t base = (size_t)bucket * scap + tid;
        const unsigned short lv = lxy[base];
        lx = lv & 63;
        ly = (lv >> 8) & 31;
        const float4* sp = (const float4*)(slots + base * 16);
        float4 a = sp[0], b2 = sp[1], c = sp[2], d = sp[3];
        f[0]=a.x; f[1]=a.y; f[2]=a.z; f[3]=a.w;
        f[4]=b2.x; f[5]=b2.y; f[6]=b2.z; f[7]=b2.w;
        f[8]=c.x; f[9]=c.y; f[10]=c.z; f[11]=c.w;
        f[12]=d.x; f[13]=d.y; f[14]=d.z; f[15]=d.w;
    }

    for (int i = tid; i < O_ * PLANE; i += 512) accs[i] = 0.f;
    __syncthreads();

    if (active) {
        float* cell = &accs[ly * EX + lx];
        #pragma unroll
        for (int o = 0; o < O_; ++o) atomicAdd(cell + o * PLANE, f[o]);
    }
    __syncthreads();

    // conv: thread = (o = tid>>5, x = tid&31); rolling vertical window.
    const int x = tid & 31;
    const int o = tid >> 5;
    const float* pl = &accs[o * PLANE + x];
    float hA2 = 0.f, hA1 = 0.f, hB1 = 0.f;
    const int x0 = tx * TSX, y0 = ty * TSY;
    const size_t obase = (((size_t)(b * O_ + o)) * H_) * W_;

    #pragma unroll
    for (int iy = 0; iy < EY; ++iy) {
        float l = pl[iy * EX], c = pl[iy * EX + 1], r = pl[iy * EX + 2];
        float sfx = l + r;
        float hA = fmaf(0.075f, sfx, 0.125f * c);
        float hB = fmaf(0.125f, sfx, 0.3f * c);
        if (iy >= 2) {
            float v = hA2 + hB1 + hA;
            size_t oi = obase + (size_t)(y0 + iy - 2) * W_ + (x0 + x);
            if (fp32) __builtin_nontemporal_store(v, (float*)out + oi);
            else      __builtin_nontemporal_store(f2bf(v), (unsigned short*)out + oi);
        }
        hA2 = hA1; hA1 = hA; hB1 = hB;
    }
}

// ===========================================================================
// PRE fallback path (round-1 kernels, used when ws is too small for SCAT)
// ===========================================================================
template<bool PRE>
__global__ __launch_bounds__(256) void fill_bins(
    const void* __restrict__ feat, const void* __restrict__ xy,
    const int* __restrict__ types,
    const void* __restrict__ w_obj, const void* __restrict__ w_prior,
    int* __restrict__ cursor, int* __restrict__ ids, float* __restrict__ p)
{
    __shared__ int hist[NTX * NTY];
    __shared__ unsigned int rec[FCHUNK];
    __shared__ float wl[PRE ? 2 * O_ * C_ : 2];

    const int tid = threadIdx.x;
    const int fp32 = probe_fp32_ballot((const unsigned int*)xy);
    for (int j = tid; j < NTX * NTY; j += 256) hist[j] = 0;
    if constexpr (PRE) load_weights_lds(wl, fp32, w_obj, w_prior, tid, 256);
    __syncthreads();

    const int bb = blockIdx.x / FPB;
    const int local0 = (blockIdx.x % FPB) * FCHUNK;
    const int s = bb * K_ + local0;

    for (int ii = tid; ii < FCHUNK; ii += 256) {
        const int n = s + ii;
        int xs, ys; decode_xy(xy, fp32, n, xs, ys);
        const int t = (types[n] != 0);
        rec[ii] = (unsigned)(xs | (ys << 9) | (t << 18));

        if constexpr (PRE) {
            float f[16];
            load_feat16(feat, (size_t)n, fp32, f);
            const float* wrow = &wl[t * O_ * C_];
            float pv[16];
            #pragma unroll
            for (int o = 0; o < O_; ++o) {
                float acc = 0.f;
                #pragma unroll
                for (int c = 0; c < C_; ++c) acc = fmaf(wrow[o * C_ + c], f[c], acc);
                pv[o] = acc;
            }
            float4* pout = (float4*)(p + (size_t)n * O_);
            pout[0] = make_float4(pv[0],  pv[1],  pv[2],  pv[3]);
            pout[1] = make_float4(pv[4],  pv[5],  pv[6],  pv[7]);
            pout[2] = make_float4(pv[8],  pv[9],  pv[10], pv[11]);
            pout[3] = make_float4(pv[12], pv[13], pv[14], pv[15]);
        }

        int xlo = max((xs - 1) >> 5, 0), xhi = min((xs + 1) >> 5, NTX - 1);
        int ylo = max((ys - 1) >> 4, 0), yhi = min((ys + 1) >> 4, NTY - 1);
        for (int tyy = ylo; tyy <= yhi; ++tyy)
            for (int txx = xlo; txx <= xhi; ++txx)
                atomicAdd(&hist[tyy * NTX + txx], 1);
    }
    __syncthreads();

    for (int j = tid; j < NTX * NTY; j += 256) {
        int c = hist[j];
        hist[j] = c ? atomicAdd(&cursor[bb * NTX * NTY + j], c) : 0;
    }
    __syncthreads();

    for (int ii = tid; ii < FCHUNK; ii += 256) {
        unsigned r = rec[ii];
        int xs = r & 511, ys = (r >> 9) & 511, t = (r >> 18) & 1;
        int local = local0 + ii;
        int xlo = max((xs - 1) >> 5, 0), xhi = min((xs + 1) >> 5, NTX - 1);
        int ylo = max((ys - 1) >> 4, 0), yhi = min((ys + 1) >> 4, NTY - 1);
        for (int tyy = ylo; tyy <= yhi; ++tyy)
            for (int txx = xlo; txx <= xhi; ++txx) {
                int bk = tyy * NTX + txx;
                int slot = atomicAdd(&hist[bk], 1);
                if (slot < CAP) {
                    int lx = xs - (txx << 5) + 1;
                    int ly = ys - (tyy << 4) + 1;
                    ids[(bb * NTX * NTY + bk) * CAP + slot] =
                        local | (t << 17) | (lx << 18) | (ly << 24);
                }
            }
    }
}

template<bool PRE>
__global__ __launch_bounds__(512) void tile_fused(
    const void* __restrict__ src, const void* __restrict__ xy,
    const void* __restrict__ w_obj, const void* __restrict__ w_prior,
    const int* __restrict__ cursor, const int* __restrict__ ids,
    void* __restrict__ out)
{
    __shared__ float accs[O_ * PLANE];
    __shared__ float wl[PRE ? 2 : 2 * O_ * C_];

    const int tid = threadIdx.x;
    const int tx = blockIdx.x, ty = blockIdx.y, b = blockIdx.z;
    const int bucket = (b * NTY + ty) * NTX + tx;
    int cnt = cursor[bucket];
    if (cnt > CAP) cnt = CAP;
    const int fp32 = probe_fp32_ballot((const unsigned int*)xy);

    float f[16];
    int t = 0, lx = 0, ly = 0;
    const bool active = (tid < cnt);
    if (active) {
        const unsigned pck = (unsigned)ids[bucket * CAP + tid];
        const int local = pck & 0x1FFFF;
        t  = (pck >> 17) & 1;
        lx = (pck >> 18) & 63;
        ly = (pck >> 24) & 31;
        const size_t n = (size_t)b * K_ + local;
        if constexpr (PRE) {
            const float4* pp = (const float4*)src + n * 4;
            float4 a = pp[0], b2 = pp[1], c = pp[2], d = pp[3];
            f[0]=a.x; f[1]=a.y; f[2]=a.z; f[3]=a.w;
            f[4]=b2.x; f[5]=b2.y; f[6]=b2.z; f[7]=b2.w;
            f[8]=c.x; f[9]=c.y; f[10]=c.z; f[11]=c.w;
            f[12]=d.x; f[13]=d.y; f[14]=d.z; f[15]=d.w;
        } else {
            load_feat16(src, n, fp32, f);
        }
    }

    for (int i = tid; i < O_ * PLANE; i += 512) accs[i] = 0.f;
    if constexpr (!PRE) load_weights_lds(wl, fp32, w_obj, w_prior, tid, 512);
    __syncthreads();

    if (active) {
        float* cell = &accs[ly * EX + lx];
        if constexpr (PRE) {
            #pragma unroll
            for (int o = 0; o < O_; ++o) atomicAdd(cell + o * PLANE, f[o]);
        } else {
            const float* wrow = &wl[t * O_ * C_];
            #pragma unroll
            for (int o = 0; o < O_; ++o) {
                float acc = 0.f;
                #pragma unroll
                for (int c = 0; c < C_; ++c) acc = fmaf(wrow[o * C_ + c], f[c], acc);
                atomicAdd(cell + o * PLANE, acc);
            }
        }
    }
    __syncthreads();

    const int x = tid & 31;
    const int o = tid >> 5;
    const float* pl = &accs[o * PLANE + x];
    float hA2 = 0.f, hA1 = 0.f, hB1 = 0.f;
    const int x0 = tx * TSX, y0 = ty * TSY;
    const size_t obase = (((size_t)(b * O_ + o)) * H_) * W_;

    #pragma unroll
    for (int iy = 0; iy < EY; ++iy) {
        float l = pl[iy * EX], c = pl[iy * EX + 1], r = pl[iy * EX + 2];
        float sfx = l + r;
        float hA = fmaf(0.075f, sfx, 0.125f * c);
        float hB = fmaf(0.125f, sfx, 0.3f * c);
        if (iy >= 2) {
            float v = hA2 + hB1 + hA;
            size_t oi = obase + (size_t)(y0 + iy - 2) * W_ + (x0 + x);
            if (fp32) __builtin_nontemporal_store(v, (float*)out + oi);
            else      __builtin_nontemporal_store(f2bf(v), (unsigned short*)out + oi);
        }
        hA2 = hA1; hA1 = hA; hB1 = hB;
    }
}

extern "C" void kernel_launch(void* const* d_in, const int* in_sizes, int n_in,
                              void* d_out, int out_size, void* d_ws, size_t ws_size,
                              hipStream_t stream)
{
    const void* feat = d_in[0];                    // [8,100000,16] fp32 (or bf16)
    const void* xy = d_in[1];                      // [8,100000,2]
    // d_in[2] = hw (int64 [2]) -- constants 512x512, unused
    const int* types = (const int*)d_in[3];        // int32 [8,100000]
    const void* w_obj = d_in[4];                   // [16,16]
    const void* w_prior = d_in[5];                 // [16,16]

    int* cursor = (int*)d_ws;
    hipMemsetAsync(cursor, 0, NBKT * sizeof(int), stream);

    // Tier 1/2: SCAT (payload-in-slot). scap=512 is 18-sigma; 384 is ~10-sigma
    // over lambda=233 -- both astronomically safe for uniform xy.
    int scap = 0;
    if (ws_size >= ws_need_scat(512)) scap = 512;
    else if (ws_size >= ws_need_scat(384)) scap = 384;

    if (scap) {
        unsigned short* lxy = (unsigned short*)((char*)d_ws + LXY_OFF);
        float* slots = (float*)((char*)d_ws + LXY_OFF + (size_t)NBKT * scap * 2);
        fill_scat<<<SFB, 256, 0, stream>>>(feat, xy, types, w_obj, w_prior,
                                           cursor, slots, lxy, scap);
        tile_scat<<<dim3(NTX, NTY, B_), 512, 0, stream>>>(
            slots, lxy, xy, cursor, d_out, scap);
    } else if (ws_size >= WS_NEED_PRE) {
        int* ids = (int*)((char*)d_ws + IDS_OFF);
        float* p = (float*)((char*)d_ws + P_OFF);
        fill_bins<true><<<FB, 256, 0, stream>>>(feat, xy, types, w_obj, w_prior,
                                                cursor, ids, p);
        tile_fused<true><<<dim3(NTX, NTY, B_), 512, 0, stream>>>(
            p, xy, w_obj, w_prior, cursor, ids, d_out);
    } else {
        int* ids = (int*)((char*)d_ws + IDS_OFF);
        float* p = (float*)((char*)d_ws + P_OFF);
        fill_bins<false><<<FB, 256, 0, stream>>>(feat, xy, types, w_obj, w_prior,
                                                 cursor, ids, p);
        tile_fused<false><<<dim3(NTX, NTY, B_), 512, 0, stream>>>(
            feat, xy, w_obj, w_prior, cursor, ids, d_out);
    }
}

// Round 3
// 315.123 us; speedup vs baseline: 1.1915x; 1.1915x over previous
//
#include <hip/hip_runtime.h>

#define B_ 8
#define K_ 100000
#define NODES (B_ * K_)
#define C_ 16
#define O_ 16
#define H_ 512
#define W_ 512
#define TSX 32
#define TSY 16
#define NTX (W_ / TSX)          // 16 tile cols
#define NTY (H_ / TSY)          // 32 tile rows
#define NBKT (B_ * NTX * NTY)   // 4096 buckets
#define CAP 512                 // slots/bucket (lambda≈233 incl halo, >18 sigma)
#define EX (TSX + 2)            // 34
#define EY (TSY + 2)            // 18
#define PLANE (EX * EY)         // 612
#define ACCP 613                // padded plane: bank stride 5 -> 16 ch conflict-free

// ---- NEW path layout: padded cursors (one 64B line each) ----
#define CURP 16                                   // ints per cursor (64 B)
#define CUR_BYTES (NBKT * CURP * 4)               // 262144
#define N_IDS_OFF CUR_BYTES
#define N_P_OFF (N_IDS_OFF + NBKT * CAP * 4)      // 262144 + 8388608
#define WS_NEED_NEW ((size_t)N_P_OFF + (size_t)NODES * O_ * 4)  // 59,850,752

#define PROJ_BLKS 2048
#define BIN_PER_B 80
#define BIN_BLKS (B_ * BIN_PER_B)                 // 640
#define BCHUNK (K_ / BIN_PER_B)                   // 1250

// ---- OLD fallback layout (round-1, unpadded cursor at 0, ids at 16K) ----
#define FB 1000
#define FPB (FB / B_)           // 125
#define FCHUNK (K_ / FPB)       // 800
#define O_IDS_OFF 16384
#define O_P_OFF (O_IDS_OFF + NBKT * CAP * 4)
#define WS_NEED_PRE ((size_t)O_P_OFF + (size_t)NODES * O_ * 4)

__device__ __forceinline__ float bf_lo(unsigned int u) {
    union { unsigned int i; float f; } v; v.i = u << 16; return v.f;
}
__device__ __forceinline__ float bf_hi(unsigned int u) {
    union { unsigned int i; float f; } v; v.i = u & 0xffff0000u; return v.f;
}
__device__ __forceinline__ unsigned short f2bf(float f) {
    union { float f; unsigned int u; } v; v.f = f;
    unsigned int u = v.u;
    u += 0x7fffu + ((u >> 16) & 1u);   // round-to-nearest-even
    return (unsigned short)(u >> 16);
}

// Barrier-free dtype probe: bf16 xy pairs always decode (low half) into
// [0,512]; fp32 low halves are random mantissa -> P(all 256 pass)≈1e-146.
__device__ __forceinline__ int probe_fp32_ballot(const unsigned int* xy) {
    const int lane = threadIdx.x & 63;
    int bad = 0;
    #pragma unroll
    for (int k = 0; k < 4; ++k) {
        float lo = bf_lo(xy[lane + (k << 6)]);
        bad |= !(lo >= 0.0f && lo <= 512.0f);
    }
    return __ballot(bad) != 0ull;
}

__device__ __forceinline__ void decode_xy(const void* xy, int fp32, int n,
                                          int& xs, int& ys)
{
    float x, y;
    if (fp32) { float2 p = ((const float2*)xy)[n]; x = p.x; y = p.y; }
    else { unsigned int u = ((const unsigned int*)xy)[n]; x = bf_lo(u); y = bf_hi(u); }
    xs = min(max((int)rintf(x), 0), W_ - 1);   // rintf == round-half-even == jnp.round
    ys = min(max((int)rintf(y), 0), H_ - 1);
}

__device__ __forceinline__ void load_feat16(const void* feat, size_t n, int fp32,
                                            float* f)
{
    if (fp32) {
        const float4* ff = (const float4*)feat + n * 4;
        float4 a = ff[0], b2 = ff[1], c = ff[2], d = ff[3];
        f[0]=a.x; f[1]=a.y; f[2]=a.z; f[3]=a.w;
        f[4]=b2.x; f[5]=b2.y; f[6]=b2.z; f[7]=b2.w;
        f[8]=c.x; f[9]=c.y; f[10]=c.z; f[11]=c.w;
        f[12]=d.x; f[13]=d.y; f[14]=d.z; f[15]=d.w;
    } else {
        const uint4* ff = (const uint4*)feat + n * 2;
        uint4 A = ff[0], Bv = ff[1];
        f[0]=bf_lo(A.x);  f[1]=bf_hi(A.x);  f[2]=bf_lo(A.y);  f[3]=bf_hi(A.y);
        f[4]=bf_lo(A.z);  f[5]=bf_hi(A.z);  f[6]=bf_lo(A.w);  f[7]=bf_hi(A.w);
        f[8]=bf_lo(Bv.x); f[9]=bf_hi(Bv.x); f[10]=bf_lo(Bv.y); f[11]=bf_hi(Bv.y);
        f[12]=bf_lo(Bv.z); f[13]=bf_hi(Bv.z); f[14]=bf_lo(Bv.w); f[15]=bf_hi(Bv.w);
    }
}

__device__ __forceinline__ void load_weights_lds(float* wl, int fp32,
                                                 const void* w_obj,
                                                 const void* w_prior,
                                                 int tid, int nthreads)
{
    for (int i = tid; i < 2 * O_ * C_; i += nthreads) {
        if (fp32) {
            wl[i] = (i < O_ * C_) ? ((const float*)w_obj)[i]
                                  : ((const float*)w_prior)[i - O_ * C_];
        } else {
            unsigned short raw = (i < O_ * C_)
                ? ((const unsigned short*)w_obj)[i]
                : ((const unsigned short*)w_prior)[i - O_ * C_];
            union { unsigned int u; float f; } v; v.u = ((unsigned int)raw) << 16;
            wl[i] = v.f;
        }
    }
}

// ===========================================================================
// prep: ONE dispatch, two block roles that overlap on the machine.
//  - blocks [0, PROJ_BLKS): pure-streaming projection feat -> p[n][16].
//    Coalesced reads/writes, zero atomics -> BW-bound (~20 us of traffic).
//  - blocks [PROJ_BLKS, +BIN_BLKS): binning. Reads ONLY xy+types (6.4 MB),
//    one atomicAdd per visit on a PADDED cursor (own 64B line: per-line
//    serialization 233 not 3734), writes 4B packed id. ~6 independent
//    visits/thread -> MLP hides the atomic round-trip; hides under proj.
// ===========================================================================
__global__ __launch_bounds__(256) void prep(
    const void* __restrict__ feat, const void* __restrict__ xy,
    const int* __restrict__ types,
    const void* __restrict__ w_obj, const void* __restrict__ w_prior,
    int* __restrict__ cursor, int* __restrict__ ids, float* __restrict__ p)
{
    const int tid = threadIdx.x;
    const int blk = blockIdx.x;
    const int fp32 = probe_fp32_ballot((const unsigned int*)xy);

    if (blk < PROJ_BLKS) {
        __shared__ float wl[2 * O_ * C_];
        load_weights_lds(wl, fp32, w_obj, w_prior, tid, 256);
        __syncthreads();

        for (int n = blk * 256 + tid; n < NODES; n += PROJ_BLKS * 256) {
            const int t = (types[n] != 0);
            float f[16];
            load_feat16(feat, (size_t)n, fp32, f);
            const float* wrow = &wl[t * O_ * C_];
            float pv[16];
            #pragma unroll
            for (int o = 0; o < O_; ++o) {
                float acc = 0.f;
                #pragma unroll
                for (int c = 0; c < C_; ++c) acc = fmaf(wrow[o * C_ + c], f[c], acc);
                pv[o] = acc;
            }
            float4* pout = (float4*)(p + (size_t)n * O_);   // coalesced 64B/node
            pout[0] = make_float4(pv[0],  pv[1],  pv[2],  pv[3]);
            pout[1] = make_float4(pv[4],  pv[5],  pv[6],  pv[7]);
            pout[2] = make_float4(pv[8],  pv[9],  pv[10], pv[11]);
            pout[3] = make_float4(pv[12], pv[13], pv[14], pv[15]);
        }
    } else {
        const int bblk = blk - PROJ_BLKS;          // 0..BIN_BLKS-1
        const int bb = bblk / BIN_PER_B;
        const int local0 = (bblk % BIN_PER_B) * BCHUNK;

        for (int ii = tid; ii < BCHUNK; ii += 256) {
            const int local = local0 + ii;
            const int n = bb * K_ + local;
            int xs, ys; decode_xy(xy, fp32, n, xs, ys);
            const int t = (types[n] != 0);
            const int xlo = max((xs - 1) >> 5, 0), xhi = min((xs + 1) >> 5, NTX - 1);
            const int ylo = max((ys - 1) >> 4, 0), yhi = min((ys + 1) >> 4, NTY - 1);
            for (int tyy = ylo; tyy <= yhi; ++tyy)
                for (int txx = xlo; txx <= xhi; ++txx) {
                    const int bkg = (bb * NTY + tyy) * NTX + txx;
                    const int slot = atomicAdd(&cursor[bkg * CURP], 1);
                    if (slot < CAP) {
                        const int lx = xs - (txx << 5) + 1;   // [0,33]
                        const int ly = ys - (tyy << 4) + 1;   // [0,17]
                        ids[bkg * CAP + slot] =
                            local | (t << 17) | (lx << 18) | (ly << 24);
                    }
                }
        }
    }
}

// ===========================================================================
// tile_coop: per 32x16 tile. Cooperative scatter: lane = (node-group g,
// channel ch) -> ONE coalesced p dword per lane (16 consecutive dwords per
// node, L3-resident) + ONE ds_add. All 512 lanes busy, ~ceil(cnt/32) iters,
// vs. old 233 threads x 16 SERIAL ds_adds. ACCP=613 padding: channel bank
// stride 5 -> 16 channels hit 16 distinct banks (conflict-free).
// ===========================================================================
__global__ __launch_bounds__(512) void tile_coop(
    const float* __restrict__ p, const void* __restrict__ xy,
    const int* __restrict__ cursor, const int* __restrict__ ids,
    void* __restrict__ out)
{
    __shared__ float accs[O_ * ACCP];               // 39,232 B -> 4 blocks/CU

    const int tid = threadIdx.x;
    const int tx = blockIdx.x, ty = blockIdx.y, b = blockIdx.z;
    const int bucket = (b * NTY + ty) * NTX + tx;
    int cnt = cursor[bucket * CURP];
    if (cnt > CAP) cnt = CAP;
    const int fp32 = probe_fp32_ballot((const unsigned int*)xy);

    for (int i = tid; i < O_ * ACCP; i += 512) accs[i] = 0.f;
    __syncthreads();

    const int g  = tid >> 4;     // node-group lane 0..31
    const int ch = tid & 15;     // channel
    const int* idbase = ids + bucket * CAP;
    #pragma unroll 2
    for (int i0 = 0; i0 < cnt; i0 += 32) {
        const int i = i0 + g;
        if (i < cnt) {
            const unsigned pck = (unsigned)idbase[i];   // broadcast per 16 lanes
            const int local = pck & 0x1FFFF;
            const int lx = (pck >> 18) & 63;
            const int ly = (pck >> 24) & 31;
            const float v = p[((size_t)b * K_ + local) * O_ + ch];
            atomicAdd(&accs[ch * ACCP + ly * EX + lx], v);
        }
    }
    __syncthreads();

    // conv: thread = (o = tid>>5, x = tid&31); rolling vertical window.
    const int x = tid & 31;
    const int o = tid >> 5;
    const float* pl = &accs[o * ACCP + x];
    float hA2 = 0.f, hA1 = 0.f, hB1 = 0.f;
    const int x0 = tx * TSX, y0 = ty * TSY;
    const size_t obase = (((size_t)(b * O_ + o)) * H_) * W_;

    #pragma unroll
    for (int iy = 0; iy < EY; ++iy) {
        float l = pl[iy * EX], c = pl[iy * EX + 1], r = pl[iy * EX + 2];
        float sfx = l + r;
        float hA = fmaf(0.075f, sfx, 0.125f * c);
        float hB = fmaf(0.125f, sfx, 0.3f * c);
        if (iy >= 2) {
            float v = hA2 + hB1 + hA;
            size_t oi = obase + (size_t)(y0 + iy - 2) * W_ + (x0 + x);
            if (fp32) __builtin_nontemporal_store(v, (float*)out + oi);
            else      __builtin_nontemporal_store(f2bf(v), (unsigned short*)out + oi);
        }
        hA2 = hA1; hA1 = hA; hB1 = hB;
    }
}

// ===========================================================================
// Fallback path (round-1 kernels, only if ws is unexpectedly small)
// ===========================================================================
template<bool PRE>
__global__ __launch_bounds__(256) void fill_bins(
    const void* __restrict__ feat, const void* __restrict__ xy,
    const int* __restrict__ types,
    const void* __restrict__ w_obj, const void* __restrict__ w_prior,
    int* __restrict__ cursor, int* __restrict__ ids, float* __restrict__ p)
{
    __shared__ int hist[NTX * NTY];
    __shared__ unsigned int rec[FCHUNK];
    __shared__ float wl[PRE ? 2 * O_ * C_ : 2];

    const int tid = threadIdx.x;
    const int fp32 = probe_fp32_ballot((const unsigned int*)xy);
    for (int j = tid; j < NTX * NTY; j += 256) hist[j] = 0;
    if constexpr (PRE) load_weights_lds(wl, fp32, w_obj, w_prior, tid, 256);
    __syncthreads();

    const int bb = blockIdx.x / FPB;
    const int local0 = (blockIdx.x % FPB) * FCHUNK;
    const int s = bb * K_ + local0;

    for (int ii = tid; ii < FCHUNK; ii += 256) {
        const int n = s + ii;
        int xs, ys; decode_xy(xy, fp32, n, xs, ys);
        const int t = (types[n] != 0);
        rec[ii] = (unsigned)(xs | (ys << 9) | (t << 18));

        if constexpr (PRE) {
            float f[16];
            load_feat16(feat, (size_t)n, fp32, f);
            const float* wrow = &wl[t * O_ * C_];
            float pv[16];
            #pragma unroll
            for (int o = 0; o < O_; ++o) {
                float acc = 0.f;
                #pragma unroll
                for (int c = 0; c < C_; ++c) acc = fmaf(wrow[o * C_ + c], f[c], acc);
                pv[o] = acc;
            }
            float4* pout = (float4*)(p + (size_t)n * O_);
            pout[0] = make_float4(pv[0],  pv[1],  pv[2],  pv[3]);
            pout[1] = make_float4(pv[4],  pv[5],  pv[6],  pv[7]);
            pout[2] = make_float4(pv[8],  pv[9],  pv[10], pv[11]);
            pout[3] = make_float4(pv[12], pv[13], pv[14], pv[15]);
        }

        int xlo = max((xs - 1) >> 5, 0), xhi = min((xs + 1) >> 5, NTX - 1);
        int ylo = max((ys - 1) >> 4, 0), yhi = min((ys + 1) >> 4, NTY - 1);
        for (int tyy = ylo; tyy <= yhi; ++tyy)
            for (int txx = xlo; txx <= xhi; ++txx)
                atomicAdd(&hist[tyy * NTX + txx], 1);
    }
    __syncthreads();

    for (int j = tid; j < NTX * NTY; j += 256) {
        int c = hist[j];
        hist[j] = c ? atomicAdd(&cursor[bb * NTX * NTY + j], c) : 0;
    }
    __syncthreads();

    for (int ii = tid; ii < FCHUNK; ii += 256) {
        unsigned r = rec[ii];
        int xs = r & 511, ys = (r >> 9) & 511, t = (r >> 18) & 1;
        int local = local0 + ii;
        int xlo = max((xs - 1) >> 5, 0), xhi = min((xs + 1) >> 5, NTX - 1);
        int ylo = max((ys - 1) >> 4, 0), yhi = min((ys + 1) >> 4, NTY - 1);
        for (int tyy = ylo; tyy <= yhi; ++tyy)
            for (int txx = xlo; txx <= xhi; ++txx) {
                int bk = tyy * NTX + txx;
                int slot = atomicAdd(&hist[bk], 1);
                if (slot < CAP) {
                    int lx = xs - (txx << 5) + 1;
                    int ly = ys - (tyy << 4) + 1;
                    ids[(bb * NTX * NTY + bk) * CAP + slot] =
                        local | (t << 17) | (lx << 18) | (ly << 24);
                }
            }
    }
}

template<bool PRE>
__global__ __launch_bounds__(512) void tile_fused(
    const void* __restrict__ src, const void* __restrict__ xy,
    const void* __restrict__ w_obj, const void* __restrict__ w_prior,
    const int* __restrict__ cursor, const int* __restrict__ ids,
    void* __restrict__ out)
{
    __shared__ float accs[O_ * PLANE];
    __shared__ float wl[PRE ? 2 : 2 * O_ * C_];

    const int tid = threadIdx.x;
    const int tx = blockIdx.x, ty = blockIdx.y, b = blockIdx.z;
    const int bucket = (b * NTY + ty) * NTX + tx;
    int cnt = cursor[bucket];
    if (cnt > CAP) cnt = CAP;
    const int fp32 = probe_fp32_ballot((const unsigned int*)xy);

    float f[16];
    int t = 0, lx = 0, ly = 0;
    const bool active = (tid < cnt);
    if (active) {
        const unsigned pck = (unsigned)ids[bucket * CAP + tid];
        const int local = pck & 0x1FFFF;
        t  = (pck >> 17) & 1;
        lx = (pck >> 18) & 63;
        ly = (pck >> 24) & 31;
        const size_t n = (size_t)b * K_ + local;
        if constexpr (PRE) {
            const float4* pp = (const float4*)src + n * 4;
            float4 a = pp[0], b2 = pp[1], c = pp[2], d = pp[3];
            f[0]=a.x; f[1]=a.y; f[2]=a.z; f[3]=a.w;
            f[4]=b2.x; f[5]=b2.y; f[6]=b2.z; f[7]=b2.w;
            f[8]=c.x; f[9]=c.y; f[10]=c.z; f[11]=c.w;
            f[12]=d.x; f[13]=d.y; f[14]=d.z; f[15]=d.w;
        } else {
            load_feat16(src, n, fp32, f);
        }
    }

    for (int i = tid; i < O_ * PLANE; i += 512) accs[i] = 0.f;
    if constexpr (!PRE) load_weights_lds(wl, fp32, w_obj, w_prior, tid, 512);
    __syncthreads();

    if (active) {
        float* cell = &accs[ly * EX + lx];
        if constexpr (PRE) {
            #pragma unroll
            for (int o = 0; o < O_; ++o) atomicAdd(cell + o * PLANE, f[o]);
        } else {
            const float* wrow = &wl[t * O_ * C_];
            #pragma unroll
            for (int o = 0; o < O_; ++o) {
                float acc = 0.f;
                #pragma unroll
                for (int c = 0; c < C_; ++c) acc = fmaf(wrow[o * C_ + c], f[c], acc);
                atomicAdd(cell + o * PLANE, acc);
            }
        }
    }
    __syncthreads();

    const int x = tid & 31;
    const int o = tid >> 5;
    const float* pl = &accs[o * PLANE + x];
    float hA2 = 0.f, hA1 = 0.f, hB1 = 0.f;
    const int x0 = tx * TSX, y0 = ty * TSY;
    const size_t obase = (((size_t)(b * O_ + o)) * H_) * W_;

    #pragma unroll
    for (int iy = 0; iy < EY; ++iy) {
        float l = pl[iy * EX], c = pl[iy * EX + 1], r = pl[iy * EX + 2];
        float sfx = l + r;
        float hA = fmaf(0.075f, sfx, 0.125f * c);
        float hB = fmaf(0.125f, sfx, 0.3f * c);
        if (iy >= 2) {
            float v = hA2 + hB1 + hA;
            size_t oi = obase + (size_t)(y0 + iy - 2) * W_ + (x0 + x);
            if (fp32) __builtin_nontemporal_store(v, (float*)out + oi);
            else      __builtin_nontemporal_store(f2bf(v), (unsigned short*)out + oi);
        }
        hA2 = hA1; hA1 = hA; hB1 = hB;
    }
}

extern "C" void kernel_launch(void* const* d_in, const int* in_sizes, int n_in,
                              void* d_out, int out_size, void* d_ws, size_t ws_size,
                              hipStream_t stream)
{
    const void* feat = d_in[0];                    // [8,100000,16] fp32 (or bf16)
    const void* xy = d_in[1];                      // [8,100000,2]
    // d_in[2] = hw (int64 [2]) -- constants 512x512, unused
    const int* types = (const int*)d_in[3];        // int32 [8,100000]
    const void* w_obj = d_in[4];                   // [16,16]
    const void* w_prior = d_in[5];                 // [16,16]

    if (ws_size >= WS_NEED_NEW) {
        int* cursor = (int*)d_ws;                  // padded: one 64B line each
        int* ids = (int*)((char*)d_ws + N_IDS_OFF);
        float* p = (float*)((char*)d_ws + N_P_OFF);
        hipMemsetAsync(cursor, 0, CUR_BYTES, stream);
        prep<<<PROJ_BLKS + BIN_BLKS, 256, 0, stream>>>(
            feat, xy, types, w_obj, w_prior, cursor, ids, p);
        tile_coop<<<dim3(NTX, NTY, B_), 512, 0, stream>>>(
            p, xy, cursor, ids, d_out);
    } else if (ws_size >= WS_NEED_PRE) {
        int* cursor = (int*)d_ws;
        int* ids = (int*)((char*)d_ws + O_IDS_OFF);
        float* p = (float*)((char*)d_ws + O_P_OFF);
        hipMemsetAsync(cursor, 0, NBKT * sizeof(int), stream);
        fill_bins<true><<<FB, 256, 0, stream>>>(feat, xy, types, w_obj, w_prior,
                                                cursor, ids, p);
        tile_fused<true><<<dim3(NTX, NTY, B_), 512, 0, stream>>>(
            p, xy, w_obj, w_prior, cursor, ids, d_out);
    } else {
        int* cursor = (int*)d_ws;
        int* ids = (int*)((char*)d_ws + O_IDS_OFF);
        float* p = (float*)((char*)d_ws + O_P_OFF);
        hipMemsetAsync(cursor, 0, NBKT * sizeof(int), stream);
        fill_bins<false><<<FB, 256, 0, stream>>>(feat, xy, types, w_obj, w_prior,
                                                 cursor, ids, p);
        tile_fused<false><<<dim3(NTX, NTY, B_), 512, 0, stream>>>(
            feat, xy, w_obj, w_prior, cursor, ids, d_out);
    }
}

// Round 4
// 303.091 us; speedup vs baseline: 1.2388x; 1.0397x over previous
//
#include <hip/hip_runtime.h>

#define B_ 8
#define K_ 100000
#define NODES (B_ * K_)
#define C_ 16
#define O_ 16
#define H_ 512
#define W_ 512
#define TSX 32
#define TSY 16
#define NTX (W_ / TSX)          // 16 tile cols
#define NTY (H_ / TSY)          // 32 tile rows
#define NBKT (B_ * NTX * NTY)   // 4096 buckets
#define CAP 512                 // slots/bucket (lambda≈233 incl halo, >18 sigma)
#define EX (TSX + 2)            // 34
#define EY (TSY + 2)            // 18
#define PLANE (EX * EY)         // 612

#define FB 1000                 // fill_bins blocks (125/batch, ~15 waves/CU)
#define FPB (FB / B_)           // 125
#define FCHUNK (K_ / FPB)       // 800

// Padded cursors: one 64B line per bucket -> reserve-phase same-line RMW
// serialization drops 2000 -> 125 per line (round-3 prep validated padding).
#define CURP 16                                   // ints per cursor (64 B)
#define CUR_BYTES (NBKT * CURP * 4)               // 262144
#define IDS_OFF CUR_BYTES
#define P_OFF (IDS_OFF + NBKT * CAP * 4)          // 262144 + 8388608
#define WS_NEED_PRE ((size_t)P_OFF + (size_t)NODES * O_ * 4)  // ~59.9 MB
#define WS_NEED_MIN ((size_t)P_OFF)               // non-PRE: cursor+ids only

__device__ __forceinline__ float bf_lo(unsigned int u) {
    union { unsigned int i; float f; } v; v.i = u << 16; return v.f;
}
__device__ __forceinline__ float bf_hi(unsigned int u) {
    union { unsigned int i; float f; } v; v.i = u & 0xffff0000u; return v.f;
}
__device__ __forceinline__ unsigned short f2bf(float f) {
    union { float f; unsigned int u; } v; v.f = f;
    unsigned int u = v.u;
    u += 0x7fffu + ((u >> 16) & 1u);   // round-to-nearest-even
    return (unsigned short)(u >> 16);
}

// Barrier-free dtype probe: bf16 xy pairs always decode (low half) into
// [0,512]; fp32 low halves are random mantissa -> P(all 256 pass)≈1e-146.
__device__ __forceinline__ int probe_fp32_ballot(const unsigned int* xy) {
    const int lane = threadIdx.x & 63;
    int bad = 0;
    #pragma unroll
    for (int k = 0; k < 4; ++k) {
        float lo = bf_lo(xy[lane + (k << 6)]);
        bad |= !(lo >= 0.0f && lo <= 512.0f);
    }
    return __ballot(bad) != 0ull;
}

__device__ __forceinline__ void decode_xy(const void* xy, int fp32, int n,
                                          int& xs, int& ys)
{
    float x, y;
    if (fp32) { float2 p = ((const float2*)xy)[n]; x = p.x; y = p.y; }
    else { unsigned int u = ((const unsigned int*)xy)[n]; x = bf_lo(u); y = bf_hi(u); }
    xs = min(max((int)rintf(x), 0), W_ - 1);   // rintf == round-half-even == jnp.round
    ys = min(max((int)rintf(y), 0), H_ - 1);
}

__device__ __forceinline__ void load_feat16(const void* feat, size_t n, int fp32,
                                            float* f)
{
    if (fp32) {
        const float4* ff = (const float4*)feat + n * 4;
        float4 a = ff[0], b2 = ff[1], c = ff[2], d = ff[3];
        f[0]=a.x; f[1]=a.y; f[2]=a.z; f[3]=a.w;
        f[4]=b2.x; f[5]=b2.y; f[6]=b2.z; f[7]=b2.w;
        f[8]=c.x; f[9]=c.y; f[10]=c.z; f[11]=c.w;
        f[12]=d.x; f[13]=d.y; f[14]=d.z; f[15]=d.w;
    } else {
        const uint4* ff = (const uint4*)feat + n * 2;
        uint4 A = ff[0], Bv = ff[1];
        f[0]=bf_lo(A.x);  f[1]=bf_hi(A.x);  f[2]=bf_lo(A.y);  f[3]=bf_hi(A.y);
        f[4]=bf_lo(A.z);  f[5]=bf_hi(A.z);  f[6]=bf_lo(A.w);  f[7]=bf_hi(A.w);
        f[8]=bf_lo(Bv.x); f[9]=bf_hi(Bv.x); f[10]=bf_lo(Bv.y); f[11]=bf_hi(Bv.y);
        f[12]=bf_lo(Bv.z); f[13]=bf_hi(Bv.z); f[14]=bf_lo(Bv.w); f[15]=bf_hi(Bv.w);
    }
}

__device__ __forceinline__ void load_weights_lds(float* wl, int fp32,
                                                 const void* w_obj,
                                                 const void* w_prior,
                                                 int tid, int nthreads)
{
    for (int i = tid; i < 2 * O_ * C_; i += nthreads) {
        if (fp32) {
            wl[i] = (i < O_ * C_) ? ((const float*)w_obj)[i]
                                  : ((const float*)w_prior)[i - O_ * C_];
        } else {
            unsigned short raw = (i < O_ * C_)
                ? ((const unsigned short*)w_obj)[i]
                : ((const unsigned short*)w_prior)[i - O_ * C_];
            union { unsigned int u; float f; } v; v.u = ((unsigned int)raw) << 16;
            wl[i] = v.f;
        }
    }
}

// ---------------------------------------------------------------------------
// Pass 1: bin nodes + (PRE) project feat through W_{type} into p[n][16].
// LDS histogram -> ONE padded-cursor reserve atomic per (block,bucket)
// (125 same-line RMWs per 64B line instead of 2000) -> per-visit LDS slot.
// ---------------------------------------------------------------------------
template<bool PRE>
__global__ __launch_bounds__(256) void fill_bins(
    const void* __restrict__ feat, const void* __restrict__ xy,
    const int* __restrict__ types,
    const void* __restrict__ w_obj, const void* __restrict__ w_prior,
    int* __restrict__ cursor, int* __restrict__ ids, float* __restrict__ p)
{
    __shared__ int hist[NTX * NTY];
    __shared__ unsigned int rec[FCHUNK];
    __shared__ float wl[PRE ? 2 * O_ * C_ : 2];

    const int tid = threadIdx.x;
    const int fp32 = probe_fp32_ballot((const unsigned int*)xy);
    for (int j = tid; j < NTX * NTY; j += 256) hist[j] = 0;
    if constexpr (PRE) load_weights_lds(wl, fp32, w_obj, w_prior, tid, 256);
    __syncthreads();

    const int bb = blockIdx.x / FPB;
    const int local0 = (blockIdx.x % FPB) * FCHUNK;
    const int s = bb * K_ + local0;

    for (int ii = tid; ii < FCHUNK; ii += 256) {
        const int n = s + ii;
        int xs, ys; decode_xy(xy, fp32, n, xs, ys);
        const int t = (types[n] != 0);
        rec[ii] = (unsigned)(xs | (ys << 9) | (t << 18));

        if constexpr (PRE) {
            float f[16];
            load_feat16(feat, (size_t)n, fp32, f);
            const float* wrow = &wl[t * O_ * C_];
            float pv[16];
            #pragma unroll
            for (int o = 0; o < O_; ++o) {
                float acc = 0.f;
                #pragma unroll
                for (int c = 0; c < C_; ++c) acc = fmaf(wrow[o * C_ + c], f[c], acc);
                pv[o] = acc;
            }
            float4* pout = (float4*)(p + (size_t)n * O_);   // coalesced 64B/node
            pout[0] = make_float4(pv[0],  pv[1],  pv[2],  pv[3]);
            pout[1] = make_float4(pv[4],  pv[5],  pv[6],  pv[7]);
            pout[2] = make_float4(pv[8],  pv[9],  pv[10], pv[11]);
            pout[3] = make_float4(pv[12], pv[13], pv[14], pv[15]);
        }

        int xlo = max((xs - 1) >> 5, 0), xhi = min((xs + 1) >> 5, NTX - 1);
        int ylo = max((ys - 1) >> 4, 0), yhi = min((ys + 1) >> 4, NTY - 1);
        for (int tyy = ylo; tyy <= yhi; ++tyy)
            for (int txx = xlo; txx <= xhi; ++txx)
                atomicAdd(&hist[tyy * NTX + txx], 1);
    }
    __syncthreads();

    for (int j = tid; j < NTX * NTY; j += 256) {
        int c = hist[j];
        // padded cursor: each bucket owns a full 64B line
        hist[j] = c ? atomicAdd(&cursor[(bb * NTX * NTY + j) * CURP], c) : 0;
    }
    __syncthreads();

    for (int ii = tid; ii < FCHUNK; ii += 256) {
        unsigned r = rec[ii];
        int xs = r & 511, ys = (r >> 9) & 511, t = (r >> 18) & 1;
        int local = local0 + ii;                       // 17 bits (<100000)
        int xlo = max((xs - 1) >> 5, 0), xhi = min((xs + 1) >> 5, NTX - 1);
        int ylo = max((ys - 1) >> 4, 0), yhi = min((ys + 1) >> 4, NTY - 1);
        for (int tyy = ylo; tyy <= yhi; ++tyy)
            for (int txx = xlo; txx <= xhi; ++txx) {
                int bk = tyy * NTX + txx;
                int slot = atomicAdd(&hist[bk], 1);    // base + local index
                if (slot < CAP) {
                    int lx = xs - (txx << 5) + 1;      // [0,33] 6 bits
                    int ly = ys - (tyy << 4) + 1;      // [0,17] 5 bits
                    ids[(bb * NTX * NTY + bk) * CAP + slot] =
                        local | (t << 17) | (lx << 18) | (ly << 24);
                }
            }
    }
}

// ---------------------------------------------------------------------------
// Pass 2 (fused): per 32x16 tile. WAVE-SPREAD gather: node = ((tid&7)<<6)|
// (tid>>3) maps the ~233 active slots evenly across all 8 waves (~29 active
// lanes each) instead of packing them into waves 0-3. Doubles the number of
// waves issuing gather instructions (2x outstanding misses per SIMD) and
// removes the barrier convoy where waves 4-7 idled through gather+scatter.
// ---------------------------------------------------------------------------
template<bool PRE>
__global__ __launch_bounds__(512) void tile_fused(
    const void* __restrict__ src /* p if PRE else feat */,
    const void* __restrict__ xy,
    const void* __restrict__ w_obj, const void* __restrict__ w_prior,
    const int* __restrict__ cursor, const int* __restrict__ ids,
    void* __restrict__ out)
{
    __shared__ float accs[O_ * PLANE];               // 39,168 B -> 4 blocks/CU
    __shared__ float wl[PRE ? 2 : 2 * O_ * C_];

    const int tid = threadIdx.x;
    const int tx = blockIdx.x, ty = blockIdx.y, b = blockIdx.z;
    const int bucket = (b * NTY + ty) * NTX + tx;
    int cnt = cursor[bucket * CURP];
    if (cnt > CAP) cnt = CAP;
    const int fp32 = probe_fp32_ballot((const unsigned int*)xy);

    // ---- early issue: ids + payload loads; zero-fill covers their latency ----
    const int node = ((tid & 7) << 6) | (tid >> 3);  // bijective wave-spread
    const bool active = (node < cnt);
    float f[16];
    int t = 0, lx = 0, ly = 0;
    if (active) {
        const unsigned pck = (unsigned)ids[bucket * CAP + node];
        const int local = pck & 0x1FFFF;
        t  = (pck >> 17) & 1;
        lx = (pck >> 18) & 63;
        ly = (pck >> 24) & 31;
        const size_t n = (size_t)b * K_ + local;
        if constexpr (PRE) {
            const float4* pp = (const float4*)src + n * 4;
            float4 a = pp[0], b2 = pp[1], c = pp[2], d = pp[3];
            f[0]=a.x; f[1]=a.y; f[2]=a.z; f[3]=a.w;
            f[4]=b2.x; f[5]=b2.y; f[6]=b2.z; f[7]=b2.w;
            f[8]=c.x; f[9]=c.y; f[10]=c.z; f[11]=c.w;
            f[12]=d.x; f[13]=d.y; f[14]=d.z; f[15]=d.w;
        } else {
            load_feat16(src, n, fp32, f);
        }
    }

    for (int i = tid; i < O_ * PLANE; i += 512) accs[i] = 0.f;
    if constexpr (!PRE) load_weights_lds(wl, fp32, w_obj, w_prior, tid, 512);
    __syncthreads();

    if (active) {
        float* cell = &accs[ly * EX + lx];
        if constexpr (PRE) {
            #pragma unroll
            for (int o = 0; o < O_; ++o) atomicAdd(cell + o * PLANE, f[o]);
        } else {
            const float* wrow = &wl[t * O_ * C_];
            #pragma unroll
            for (int o = 0; o < O_; ++o) {
                float acc = 0.f;
                #pragma unroll
                for (int c = 0; c < C_; ++c) acc = fmaf(wrow[o * C_ + c], f[c], acc);
                atomicAdd(cell + o * PLANE, acc);
            }
        }
    }
    __syncthreads();

    // conv: thread = (o = tid>>5, x = tid&31); rolling vertical window.
    const int x = tid & 31;
    const int o = tid >> 5;
    const float* pl = &accs[o * PLANE + x];
    float hA2 = 0.f, hA1 = 0.f, hB1 = 0.f;
    const int x0 = tx * TSX, y0 = ty * TSY;
    const size_t obase = (((size_t)(b * O_ + o)) * H_) * W_;

    #pragma unroll
    for (int iy = 0; iy < EY; ++iy) {
        float l = pl[iy * EX], c = pl[iy * EX + 1], r = pl[iy * EX + 2];
        float sfx = l + r;
        float hA = fmaf(0.075f, sfx, 0.125f * c);
        float hB = fmaf(0.125f, sfx, 0.3f * c);
        if (iy >= 2) {
            float v = hA2 + hB1 + hA;
            size_t oi = obase + (size_t)(y0 + iy - 2) * W_ + (x0 + x);
            if (fp32) __builtin_nontemporal_store(v, (float*)out + oi);
            else      __builtin_nontemporal_store(f2bf(v), (unsigned short*)out + oi);
        }
        hA2 = hA1; hA1 = hA; hB1 = hB;
    }
}

extern "C" void kernel_launch(void* const* d_in, const int* in_sizes, int n_in,
                              void* d_out, int out_size, void* d_ws, size_t ws_size,
                              hipStream_t stream)
{
    const void* feat = d_in[0];                    // [8,100000,16] fp32 (or bf16)
    const void* xy = d_in[1];                      // [8,100000,2]
    // d_in[2] = hw (int64 [2]) -- constants 512x512, unused
    const int* types = (const int*)d_in[3];        // int32 [8,100000]
    const void* w_obj = d_in[4];                   // [16,16]
    const void* w_prior = d_in[5];                 // [16,16]

    int* cursor = (int*)d_ws;                      // padded: one 64B line each
    int* ids = (int*)((char*)d_ws + IDS_OFF);
    float* p = (float*)((char*)d_ws + P_OFF);

    hipMemsetAsync(cursor, 0, CUR_BYTES, stream);
    if (ws_size >= WS_NEED_PRE) {
        fill_bins<true><<<FB, 256, 0, stream>>>(feat, xy, types, w_obj, w_prior,
                                                cursor, ids, p);
        tile_fused<true><<<dim3(NTX, NTY, B_), 512, 0, stream>>>(
            p, xy, w_obj, w_prior, cursor, ids, d_out);
    } else {
        fill_bins<false><<<FB, 256, 0, stream>>>(feat, xy, types, w_obj, w_prior,
                                                 cursor, ids, p);
        tile_fused<false><<<dim3(NTX, NTY, B_), 512, 0, stream>>>(
            feat, xy, w_obj, w_prior, cursor, ids, d_out);
    }
}